// Round 1
// baseline (76.541 us; speedup 1.0000x reference)
//
#include <hip/hip_runtime.h>

// LSHAttention reference returns ONLY sticker = argsort(buckets) [B,S] int32.
// B=4, S=4096, D=1024, NR=32 (bucket_size/2), 64 buckets.
// Pipeline: K1 GEMM+argmax+chunk-hist -> K2 offset scan -> K3 stable scatter.

#define B_DIM 4
#define S_LEN 4096
#define D_DIM 1024
#define NR 32
#define NBK 64
#define TM 64
#define KB 64
#define NCHUNK (S_LEN / TM) // 64 chunks per batch

__global__ __launch_bounds__(256) void k1_buckets(
    const float* __restrict__ Q, const float* __restrict__ R,
    int* __restrict__ buckets, int* __restrict__ hist)
{
    __shared__ __align__(16) float Qs[TM][KB + 4];   // +4 pad keeps 16B align, breaks pow2 stride
    __shared__ __align__(16) float Rst[NR][KB + 4];  // R transposed: Rst[r][k]
    __shared__ float xs[TM][NR + 1];
    __shared__ int cnt[NBK];

    const int t = threadIdx.x;
    const int b = blockIdx.x / NCHUNK;
    const int chunk = blockIdx.x % NCHUNK;
    const int s0 = chunk * TM;

    const int rg = t & 15;   // 16 r-groups x 2 r
    const int tg = t >> 4;   // 16 token-groups x 4 tokens

    const float* Qb = Q + ((size_t)b * S_LEN + s0) * D_DIM;
    const float* Rb = R + (size_t)b * D_DIM * NR;

    float4 qreg[4];
    float4 rreg[2];

    // prefetch chunk 0 into registers
#pragma unroll
    for (int i = 0; i < 4; ++i) {
        int idx = t + 256 * i;
        qreg[i] = *reinterpret_cast<const float4*>(Qb + (size_t)(idx >> 4) * D_DIM + (idx & 15) * 4);
    }
#pragma unroll
    for (int i = 0; i < 2; ++i) {
        int idx = t + 256 * i;
        rreg[i] = *reinterpret_cast<const float4*>(Rb + (size_t)(idx >> 3) * NR + (idx & 7) * 4);
    }

    float acc[4][2] = {{0.f, 0.f}, {0.f, 0.f}, {0.f, 0.f}, {0.f, 0.f}};

    for (int kc = 0; kc < D_DIM / KB; ++kc) {
        // commit staged registers to LDS
#pragma unroll
        for (int i = 0; i < 4; ++i) {
            int idx = t + 256 * i;
            *reinterpret_cast<float4*>(&Qs[idx >> 4][(idx & 15) * 4]) = qreg[i];
        }
#pragma unroll
        for (int i = 0; i < 2; ++i) {
            int idx = t + 256 * i;
            int d = idx >> 3;
            int r4 = (idx & 7) * 4;
            Rst[r4 + 0][d] = rreg[i].x;
            Rst[r4 + 1][d] = rreg[i].y;
            Rst[r4 + 2][d] = rreg[i].z;
            Rst[r4 + 3][d] = rreg[i].w;
        }
        __syncthreads();
        // prefetch next chunk (overlaps with compute below)
        if (kc + 1 < D_DIM / KB) {
            int k0n = (kc + 1) * KB;
#pragma unroll
            for (int i = 0; i < 4; ++i) {
                int idx = t + 256 * i;
                qreg[i] = *reinterpret_cast<const float4*>(Qb + (size_t)(idx >> 4) * D_DIM + k0n + (idx & 15) * 4);
            }
#pragma unroll
            for (int i = 0; i < 2; ++i) {
                int idx = t + 256 * i;
                rreg[i] = *reinterpret_cast<const float4*>(Rb + (size_t)(k0n + (idx >> 3)) * NR + (idx & 7) * 4);
            }
        }
        // compute: 4 tokens x 2 r per thread, float4 LDS reads
#pragma unroll 4
        for (int kk = 0; kk < KB; kk += 4) {
            float4 r0 = *reinterpret_cast<const float4*>(&Rst[rg * 2 + 0][kk]);
            float4 r1 = *reinterpret_cast<const float4*>(&Rst[rg * 2 + 1][kk]);
#pragma unroll
            for (int j = 0; j < 4; ++j) {
                float4 q = *reinterpret_cast<const float4*>(&Qs[tg * 4 + j][kk]);
                acc[j][0] = fmaf(q.x, r0.x, acc[j][0]);
                acc[j][0] = fmaf(q.y, r0.y, acc[j][0]);
                acc[j][0] = fmaf(q.z, r0.z, acc[j][0]);
                acc[j][0] = fmaf(q.w, r0.w, acc[j][0]);
                acc[j][1] = fmaf(q.x, r1.x, acc[j][1]);
                acc[j][1] = fmaf(q.y, r1.y, acc[j][1]);
                acc[j][1] = fmaf(q.z, r1.z, acc[j][1]);
                acc[j][1] = fmaf(q.w, r1.w, acc[j][1]);
            }
        }
        __syncthreads();
    }

#pragma unroll
    for (int j = 0; j < 4; ++j) {
        xs[tg * 4 + j][rg * 2 + 0] = acc[j][0];
        xs[tg * 4 + j][rg * 2 + 1] = acc[j][1];
    }
    if (t < NBK) cnt[t] = 0;
    __syncthreads();

    if (t < TM) {
        // argmax(concat[xR,-xR]) with first-occurrence tie-break:
        // first-max of xR vs first-min of xR; ties favor the first half (>=).
        float m1 = xs[t][0]; int i1 = 0;
        float m2 = m1;       int i2 = 0;
#pragma unroll
        for (int r = 1; r < NR; ++r) {
            float v = xs[t][r];
            if (v > m1) { m1 = v; i1 = r; }
            if (v < m2) { m2 = v; i2 = r; }
        }
        int bk = (m1 >= -m2) ? i1 : (NR + i2);
        buckets[(size_t)b * S_LEN + s0 + t] = bk;
        atomicAdd(&cnt[bk], 1);
    }
    __syncthreads();
    if (t < NBK) hist[((size_t)b * NCHUNK + chunk) * NBK + t] = cnt[t];
}

// One block, 256 threads: thread = (batch b = t/64, bucket bk = t%64).
// Produces chunkOffset[b][c][bk] = global start of (bucket bk tokens of chunk c).
__global__ __launch_bounds__(256) void k2_scan(
    const int* __restrict__ hist, int* __restrict__ chunkOffset)
{
    const int t = threadIdx.x;
    const int b = t >> 6;
    const int bk = t & 63;
    const int lane = t & 63;

    int total = 0;
    for (int c = 0; c < NCHUNK; ++c)
        total += hist[((size_t)b * NCHUNK + c) * NBK + bk];

    // wave-wide inclusive scan over buckets (one wave == one batch)
    int incl = total;
#pragma unroll
    for (int off = 1; off < 64; off <<= 1) {
        int n = __shfl_up(incl, off, 64);
        if (lane >= off) incl += n;
    }
    int run = incl - total; // exclusive prefix over buckets = bucketStart

    for (int c = 0; c < NCHUNK; ++c) {
        int h = hist[((size_t)b * NCHUNK + c) * NBK + bk];
        chunkOffset[((size_t)b * NCHUNK + c) * NBK + bk] = run;
        run += h;
    }
}

// Stable scatter: wave = 64 consecutive tokens (one chunk). In-chunk rank among
// equal buckets via 6x ballot bucket-bit match + popcount of lower lanes.
__global__ __launch_bounds__(256) void k3_scatter(
    const int* __restrict__ buckets, const int* __restrict__ chunkOffset,
    int* __restrict__ out)
{
    const int gid = blockIdx.x * 256 + threadIdx.x; // 0..16383
    const int b = gid >> 12;
    const int s = gid & (S_LEN - 1);
    const int chunk = s >> 6;
    const int lane = threadIdx.x & 63;

    const int bk = buckets[gid];

    unsigned long long m = ~0ull;
#pragma unroll
    for (int i = 0; i < 6; ++i) {
        unsigned long long bi = __ballot((bk >> i) & 1);
        m &= ((bk >> i) & 1) ? bi : ~bi;
    }
    int rank = __popcll(m & ((1ull << lane) - 1ull));

    int pos = chunkOffset[((size_t)b * NCHUNK + chunk) * NBK + bk] + rank;
    out[(size_t)b * S_LEN + pos] = s;
}

extern "C" void kernel_launch(void* const* d_in, const int* in_sizes, int n_in,
                              void* d_out, int out_size, void* d_ws, size_t ws_size,
                              hipStream_t stream) {
    const float* Q = (const float*)d_in[0];
    // d_in[1] = key, d_in[2] = value: dead code in the reference, never read.
    const float* R = (const float*)d_in[3];

    int* buckets     = (int*)d_ws;                      // 16384 ints
    int* hist        = buckets + B_DIM * S_LEN;         // 16384 ints
    int* chunkOffset = hist + B_DIM * NCHUNK * NBK;     // 16384 ints

    k1_buckets<<<B_DIM * NCHUNK, 256, 0, stream>>>(Q, R, buckets, hist);
    k2_scan<<<1, 256, 0, stream>>>(hist, chunkOffset);
    k3_scatter<<<(B_DIM * S_LEN) / 256, 256, 0, stream>>>(buckets, chunkOffset, (int*)d_out);
}